// Round 10
// baseline (2570.929 us; speedup 1.0000x reference)
//
#include <hip/hip_runtime.h>

#define T_ 256
#define B_ 32
#define NL 4
#define H_ 256
#define V_ 32000
#define M_ 8192   // T_*B_

typedef float  f32x4  __attribute__((ext_vector_type(4)));
typedef short  s16x8  __attribute__((ext_vector_type(8)));
typedef __bf16 bf16x8 __attribute__((ext_vector_type(8)));

__device__ __forceinline__ unsigned short f2bf(float f) {
    unsigned u = __float_as_uint(f);
    u = (u + 0x7fffu + ((u >> 16) & 1u)) >> 16;
    return (unsigned short)u;
}

__device__ __forceinline__ f32x4 mfma16(s16x8 a, s16x8 b, f32x4 c) {
    union { s16x8 s; bf16x8 b; } ua, ub;
    ua.s = a; ub.s = b;
    return __builtin_amdgcn_mfma_f32_16x16x32_bf16(ua.b, ub.b, c, 0, 0, 0);
}

__device__ __forceinline__ float tanh_fast(float x) {
    float e = __expf(2.0f * x);
    return 1.0f - 2.0f / (e + 1.0f);   // large |x| -> +-1 via inf/0, safe
}

// convert 8 consecutive f32 -> bf16 fragment
__device__ __forceinline__ s16x8 load_w8(const float* p) {
    float4 w0 = *(const float4*)p;
    float4 w1 = *(const float4*)(p + 4);
    s16x8 f;
    f[0] = (short)f2bf(w0.x); f[1] = (short)f2bf(w0.y);
    f[2] = (short)f2bf(w0.z); f[3] = (short)f2bf(w0.w);
    f[4] = (short)f2bf(w1.x); f[5] = (short)f2bf(w1.y);
    f[6] = (short)f2bf(w1.z); f[7] = (short)f2bf(w1.w);
    return f;
}

// ---------------- flag reset (graph-replay safe) ----------------------------
__global__ __launch_bounds__(1024) void k_zero(int* __restrict__ f) {
    f[threadIdx.x] = 0;
}

// ---------------- embedding gather -> MFMA-A fragment-packed layout ---------
// packed slot t (8192 shorts): elem (m,k) at ((k>>3)*32 + m)*8 + (k&7)
__global__ __launch_bounds__(256) void k_embed(const int* __restrict__ tok,
                                               const float* __restrict__ emb,
                                               unsigned short* __restrict__ xout) {
    int row = blockIdx.x;            // t*32 + m
    int j   = threadIdx.x;           // k
    int t   = tok[row];
    int m   = row & 31;
    xout[(size_t)(row >> 5) * (B_ * H_) + ((j >> 3) * 32 + m) * 8 + (j & 7)] =
        f2bf(emb[(size_t)t * H_ + j]);
}

// ---------------- f32 -> bf16 bulk convert (dec_W) --------------------------
__global__ __launch_bounds__(256) void k_cvt(const float* __restrict__ src,
                                             unsigned short* __restrict__ dst,
                                             int n4) {
    int i = blockIdx.x * blockDim.x + threadIdx.x;
    if (i >= n4) return;
    float4 v = *(const float4*)(src + (size_t)i * 4);
    short4 o;
    o.x = (short)f2bf(v.x); o.y = (short)f2bf(v.y);
    o.z = (short)f2bf(v.z); o.w = (short)f2bf(v.w);
    *(short4*)(dst + (size_t)i * 4) = o;
}

// ---------------- pipelined 4-layer recurrence ------------------------------
// grid = 4 blocks (1 per layer), 512 threads = 8 waves; wave w owns cols
// [32w, 32w+32). Per step: h = tanh(x@Wih^T + h@Whh^T + b), x from prev
// layer's per-t handoff slot (fragment-packed, read directly as A-frags),
// h double-buffered in LDS. Cross-block sync: per-t flags, agent scope.
__global__ __launch_bounds__(512, 2) void k_pipe(const float* __restrict__ Wih,
                                                 const float* __restrict__ Whh,
                                                 const float* __restrict__ bih,
                                                 const float* __restrict__ bhh,
                                                 unsigned short* __restrict__ buf0,
                                                 unsigned short* __restrict__ hb1,
                                                 unsigned short* __restrict__ hb2,
                                                 unsigned short* __restrict__ hb3,
                                                 float* __restrict__ hid,
                                                 int* __restrict__ flags) {
    __shared__ short hbuf[2][B_ * H_];   // 2 x 16 KB

    const int l = blockIdx.x;
    const unsigned short* inb;
    unsigned short* outb;
    // layer 3 writes row-major into buf0 (aliased with embeddings; its write
    // of slot t happens-after block 0's read of slot t via the flag chain)
    if      (l == 0) { inb = buf0; outb = hb1; }
    else if (l == 1) { inb = hb1;  outb = hb2; }
    else if (l == 2) { inb = hb2;  outb = hb3; }
    else             { inb = hb3;  outb = buf0; }

    const int tid = threadIdx.x;
    const int wv = tid >> 6, ln = tid & 63;
    const int q = ln >> 4, c = ln & 15;
    const int n0 = wv * 32;

    const float* wih_l = Wih + (size_t)l * H_ * H_;
    const float* whh_l = Whh + (size_t)l * H_ * H_;

    // persistent weight fragments: ~128 VGPRs
    s16x8 fih[2][8], fhh[2][8];
    float bs[2];
#pragma unroll
    for (int nt = 0; nt < 2; ++nt) {
        int n = n0 + nt * 16 + c;
        bs[nt] = bih[l * H_ + n] + bhh[l * H_ + n];
#pragma unroll
        for (int kk = 0; kk < 8; ++kk) {
            fih[nt][kk] = load_w8(wih_l + (size_t)n * H_ + kk * 32 + q * 8);
            fhh[nt][kk] = load_w8(whh_l + (size_t)n * H_ + kk * 32 + q * 8);
        }
    }

    {   // h(-1) = 0 lives in hbuf[1] (read at t=0)
        s16x8 z = {0, 0, 0, 0, 0, 0, 0, 0};
#pragma unroll
        for (int i = tid; i < B_ * H_ / 8; i += 512)
            ((s16x8*)hbuf[1])[i] = z;
    }
    __syncthreads();

    for (int t = 0; t < T_; ++t) {
        if (l > 0) {
            int* fl = flags + (l - 1) * T_ + t;
            while (__hip_atomic_load(fl, __ATOMIC_RELAXED, __HIP_MEMORY_SCOPE_AGENT) == 0)
                __builtin_amdgcn_s_sleep(1);
            __builtin_amdgcn_fence(__ATOMIC_ACQUIRE, "agent");
        }
        const unsigned short* xin = inb + (size_t)t * (B_ * H_);
        const short* rd = hbuf[1 - (t & 1)];
        short*       wr = hbuf[t & 1];

        // issue x A-fragment loads early (L2/L3 resident, covered by h-phase)
        s16x8 xf[2][8];
#pragma unroll
        for (int mt = 0; mt < 2; ++mt)
#pragma unroll
            for (int kk = 0; kk < 8; ++kk)
                xf[mt][kk] = *(const s16x8*)(xin + ((kk * 4 + q) * 32 + mt * 16 + c) * 8);

        f32x4 acc[2][2];
#pragma unroll
        for (int mt = 0; mt < 2; ++mt)
#pragma unroll
            for (int nt = 0; nt < 2; ++nt)
                acc[mt][nt] = (f32x4){0.f, 0.f, 0.f, 0.f};

        // h @ Whh^T  (LDS A-frags; 16 ds_read_b128 per wave)
#pragma unroll
        for (int kk = 0; kk < 8; ++kk) {
            s16x8 h0 = *(const s16x8*)(rd + ((kk * 4 + q) * 32 + c) * 8);
            s16x8 h1 = *(const s16x8*)(rd + ((kk * 4 + q) * 32 + 16 + c) * 8);
            acc[0][0] = mfma16(h0, fhh[0][kk], acc[0][0]);
            acc[0][1] = mfma16(h0, fhh[1][kk], acc[0][1]);
            acc[1][0] = mfma16(h1, fhh[0][kk], acc[1][0]);
            acc[1][1] = mfma16(h1, fhh[1][kk], acc[1][1]);
        }
        // x @ Wih^T
#pragma unroll
        for (int kk = 0; kk < 8; ++kk) {
            acc[0][0] = mfma16(xf[0][kk], fih[0][kk], acc[0][0]);
            acc[0][1] = mfma16(xf[0][kk], fih[1][kk], acc[0][1]);
            acc[1][0] = mfma16(xf[1][kk], fih[0][kk], acc[1][0]);
            acc[1][1] = mfma16(xf[1][kk], fih[1][kk], acc[1][1]);
        }

        // epilogue: bias + tanh, write LDS (next h) + global handoff
#pragma unroll
        for (int mt = 0; mt < 2; ++mt)
#pragma unroll
            for (int nt = 0; nt < 2; ++nt) {
                int n = n0 + nt * 16 + c;
#pragma unroll
                for (int r = 0; r < 4; ++r) {
                    int m = mt * 16 + q * 4 + r;
                    float v = tanh_fast(acc[mt][nt][r] + bs[nt]);
                    unsigned short vb = f2bf(v);
                    wr[((n >> 3) * 32 + m) * 8 + (n & 7)] = (short)vb;   // next step's A-frag
                    if (l == 3)
                        outb[(size_t)t * (B_ * H_) + m * H_ + n] = vb;      // row-major for decode
                    else
                        outb[(size_t)t * (B_ * H_) + ((n >> 3) * 32 + m) * 8 + (n & 7)] = vb;
                    if (t == T_ - 1)
                        hid[(size_t)l * B_ * H_ + m * H_ + n] = v;
                }
            }

        __syncthreads();   // all waves' stores drained (vmcnt 0), swap h buffers
        if (l < 3 && tid == 0)
            __hip_atomic_store(flags + l * T_ + t, 1,
                               __ATOMIC_RELEASE, __HIP_MEMORY_SCOPE_AGENT);
    }
}

// ---------------- decode GEMM: out[m][v] = sum_k A[m][k]*Bm[v][k] + bias[v] -
// 128x128 block tile, K=256 single pass; 4 waves in 2x2, each 64x64
#define LDP 264   // padded row length in shorts (528 B -> conflict-free b128)
__global__ __launch_bounds__(256) void k_decode(const unsigned short* __restrict__ A,
                                                const unsigned short* __restrict__ Bm,
                                                const float* __restrict__ bias,
                                                float* __restrict__ out) {
    extern __shared__ __align__(16) short sm[];
    short* lA = sm;              // 128 x LDP
    short* lB = sm + 128 * LDP;  // 128 x LDP

    int tid = threadIdx.x;
    int n0g = blockIdx.x * 128;
    int m0g = blockIdx.y * 128;

#pragma unroll
    for (int it = 0; it < 16; ++it) {
        int u = it * 256 + tid;
        int mr = u >> 5;       // 0..127
        int ko = u & 31;       // 16B chunk within row
        *(s16x8*)(lA + mr * LDP + ko * 8) =
            *(const s16x8*)(A + (size_t)(m0g + mr) * H_ + ko * 8);
        *(s16x8*)(lB + mr * LDP + ko * 8) =
            *(const s16x8*)(Bm + (size_t)(n0g + mr) * H_ + ko * 8);
    }
    __syncthreads();

    int wv = tid >> 6, ln = tid & 63;
    int q = ln >> 4, c = ln & 15;
    int wm = (wv >> 1) * 64, wn = (wv & 1) * 64;

    f32x4 acc[4][4];
#pragma unroll
    for (int i = 0; i < 4; ++i)
#pragma unroll
        for (int j = 0; j < 4; ++j) acc[i][j] = (f32x4){0.f, 0.f, 0.f, 0.f};

#pragma unroll
    for (int kk = 0; kk < 8; ++kk) {
        s16x8 a[4], b[4];
#pragma unroll
        for (int mt = 0; mt < 4; ++mt)
            a[mt] = *(const s16x8*)(lA + (wm + mt * 16 + c) * LDP + kk * 32 + q * 8);
#pragma unroll
        for (int nt = 0; nt < 4; ++nt)
            b[nt] = *(const s16x8*)(lB + (wn + nt * 16 + c) * LDP + kk * 32 + q * 8);
#pragma unroll
        for (int mt = 0; mt < 4; ++mt)
#pragma unroll
            for (int nt = 0; nt < 4; ++nt)
                acc[mt][nt] = mfma16(a[mt], b[nt], acc[mt][nt]);
    }

#pragma unroll
    for (int nt = 0; nt < 4; ++nt) {
        int col = n0g + wn + nt * 16 + c;
        float bv = bias[col];
#pragma unroll
        for (int mt = 0; mt < 4; ++mt) {
            int row = m0g + wm + mt * 16 + q * 4;
#pragma unroll
            for (int r = 0; r < 4; ++r)
                out[(size_t)(row + r) * V_ + col] = acc[mt][nt][r] + bv;
        }
    }
}

// ---------------------------------------------------------------------------
extern "C" void kernel_launch(void* const* d_in, const int* in_sizes, int n_in,
                              void* d_out, int out_size, void* d_ws, size_t ws_size,
                              hipStream_t stream) {
    const int*   tokens = (const int*)d_in[0];
    const float* emb    = (const float*)d_in[1];
    const float* W_ih   = (const float*)d_in[2];
    const float* W_hh   = (const float*)d_in[3];
    const float* b_ih   = (const float*)d_in[4];
    const float* b_hh   = (const float*)d_in[5];
    const float* dec_W  = (const float*)d_in[6];
    const float* dec_b  = (const float*)d_in[7];

    float* out = (float*)d_out;
    float* hid = out + (size_t)M_ * V_;   // hidden [L,B,H] after decoded [T,B,V]

    char* ws = (char*)d_ws;
    unsigned short* buf0   = (unsigned short*)(ws);                  // 4 MB: emb-packed / top row-major
    unsigned short* hb1    = (unsigned short*)(ws + (4u << 20));     // 4 MB
    unsigned short* hb2    = (unsigned short*)(ws + (8u << 20));     // 4 MB
    unsigned short* hb3    = (unsigned short*)(ws + (12u << 20));    // 4 MB
    unsigned short* decW16 = (unsigned short*)(ws + (16u << 20));    // 15.63 MB
    int* flags = (int*)(ws + (16u << 20) + (size_t)V_ * H_ * sizeof(unsigned short));

    (void)in_sizes; (void)n_in; (void)out_size; (void)ws_size;

    hipFuncSetAttribute((const void*)k_decode,
                        hipFuncAttributeMaxDynamicSharedMemorySize,
                        2 * 128 * LDP * (int)sizeof(short));

    k_zero<<<1, 1024, 0, stream>>>(flags);
    k_embed<<<M_, 256, 0, stream>>>(tokens, emb, buf0);
    k_cvt<<<(V_ * H_ / 4 + 255) / 256, 256, 0, stream>>>(dec_W, decW16, V_ * H_ / 4);

    k_pipe<<<NL, 512, 0, stream>>>(W_ih, W_hh, b_ih, b_hh,
                                   buf0, hb1, hb2, hb3, hid, flags);

    k_decode<<<dim3(V_ / 128, M_ / 128), 256, 2 * 128 * LDP * sizeof(short), stream>>>(
        buf0, decW16, dec_b, out);
}